// Round 6
// baseline (311.381 us; speedup 1.0000x reference)
//
#include <hip/hip_runtime.h>
#include <hip/hip_fp16.h>

#define D      64
#define BSHIFT 9
#define BSIZE  512    // nodes per bucket
#define NBMAX  256    // supports N <= 131072
#define CAP    8192   // edge capacity per bucket (lambda ~6.1k, 26 sigma)

typedef _Float16 half8 __attribute__((ext_vector_type(8)));
typedef float    f32x4 __attribute__((ext_vector_type(4)));

__device__ __forceinline__ unsigned short f2h(float f) {
    __half h = __float2half_rn(f);
    return *reinterpret_cast<unsigned short*>(&h);
}
__device__ __forceinline__ float2 h2f2(unsigned u) {
    __half2 h = *reinterpret_cast<__half2*>(&u);
    return __half22float2(h);
}

// ===========================================================================
// Phase A: bin edges by dst-bucket (packed src|dst_low<<17) and src-bucket
// (src_low u16). LDS histograms; ~512 global atomics per block only.
// ===========================================================================
__global__ void binA_kernel(const int* __restrict__ src,
                            const int* __restrict__ dst,
                            int* __restrict__ curD, int* __restrict__ curS,
                            unsigned int* __restrict__ bufD,
                            unsigned short* __restrict__ bufS, int n_edges) {
    __shared__ int histD[NBMAX], histS[NBMAX], baseD[NBMAX], baseS[NBMAX];
    int per = (n_edges + gridDim.x - 1) / gridDim.x;
    int lo = blockIdx.x * per;
    int hi = min(lo + per, n_edges);
    int t = threadIdx.x;

    histD[t] = 0; histS[t] = 0;
    __syncthreads();
    for (int e = lo + t; e < hi; e += blockDim.x) {
        atomicAdd(&histD[dst[e] >> BSHIFT], 1);
        atomicAdd(&histS[src[e] >> BSHIFT], 1);
    }
    __syncthreads();
    baseD[t] = histD[t] ? atomicAdd(&curD[t], histD[t]) : 0;
    baseS[t] = histS[t] ? atomicAdd(&curS[t], histS[t]) : 0;
    histD[t] = 0; histS[t] = 0;
    __syncthreads();
    for (int e = lo + t; e < hi; e += blockDim.x) {
        int s = src[e], d = dst[e];
        int bd = d >> BSHIFT;
        int pd = baseD[bd] + atomicAdd(&histD[bd], 1);
        if (pd < CAP)
            bufD[(size_t)bd * CAP + pd] =
                (unsigned)s | ((unsigned)(d & (BSIZE - 1)) << 17);
        int bs = s >> BSHIFT;
        int ps = baseS[bs] + atomicAdd(&histS[bs], 1);
        if (ps < CAP) bufS[(size_t)bs * CAP + ps] =
                (unsigned short)(s & (BSIZE - 1));
    }
}

// ===========================================================================
// Phase B+C fused. blocks [0,nb): counting-sort dst-bucket in LDS, write
// dense edge list (aliases bufD), rp + cnt_in. blocks [nb,2nb): out-degree
// histogram -> norm_out.
// ===========================================================================
__global__ void __launch_bounds__(512)
binBC_kernel(const unsigned int* __restrict__ bufD,
             unsigned int* __restrict__ edgeC,        // == bufD (alias)
             const unsigned short* __restrict__ bufS,
             const int* __restrict__ curD, const int* __restrict__ curS,
             int* __restrict__ rp, int* __restrict__ cnt_in,
             float* __restrict__ norm_out, int n_nodes, int nb) {
    __shared__ int hist[BSIZE], off[BSIZE], cnt2[BSIZE];
    __shared__ int stage[CAP];
    int b = blockIdx.x, t = threadIdx.x;

    if (b < nb) {
        hist[t] = 0;
        __syncthreads();
        int m = min(curD[b], CAP);
        for (int e = t; e < m; e += 512)
            atomicAdd(&hist[bufD[(size_t)b * CAP + e] >> 17], 1);
        __syncthreads();
        int v = hist[t];
        off[t] = v;
        __syncthreads();
        for (int o = 1; o < 512; o <<= 1) {
            int x = (t >= o) ? off[t - o] : 0;
            __syncthreads();
            off[t] += x;
            __syncthreads();
        }
        int excl = off[t] - v;
        __syncthreads();
        off[t] = excl;
        cnt2[t] = 0;
        __syncthreads();
        for (int e = t; e < m; e += 512) {
            unsigned w = bufD[(size_t)b * CAP + e];
            int dl = w >> 17;
            int s  = (int)(w & 0x1FFFFu);
            int pos = off[dl] + atomicAdd(&cnt2[dl], 1);
            stage[pos] = s;
        }
        __syncthreads();
        for (int e = t; e < m; e += 512)
            edgeC[(size_t)b * CAP + e] = (unsigned)stage[e];
        int node = (b << BSHIFT) + t;
        if (node < n_nodes) {
            rp[node] = b * CAP + excl;
            cnt_in[node] = v;
        }
    } else {
        int b2 = b - nb;
        hist[t] = 0;
        __syncthreads();
        int m = min(curS[b2], CAP);
        for (int e = t; e < m; e += 512)
            atomicAdd(&hist[bufS[(size_t)b2 * CAP + e]], 1);
        __syncthreads();
        int node = (b2 << BSHIFT) + t;
        if (node < n_nodes)
            norm_out[node] = rsqrtf(fmaxf((float)hist[t], 1.0f));
    }
}

// ---- xp (fp16 packed) = x * norm_out; thread handles 8 features (16B) ----
__global__ void scale_kernel(const float* __restrict__ x,
                             const float* __restrict__ norm_out,
                             unsigned int* __restrict__ xp, int n_nodes) {
    int i = blockIdx.x * blockDim.x + threadIdx.x;
    if (i >= n_nodes * 8) return;
    int r = i >> 3;
    float no = norm_out[r];
    const float4* px = (const float4*)x + (size_t)i * 2;
    float4 v0 = px[0], v1 = px[1];
    uint4 o;
    o.x = (unsigned)f2h(v0.x * no) | ((unsigned)f2h(v0.y * no) << 16);
    o.y = (unsigned)f2h(v0.z * no) | ((unsigned)f2h(v0.w * no) << 16);
    o.z = (unsigned)f2h(v1.x * no) | ((unsigned)f2h(v1.y * no) << 16);
    o.w = (unsigned)f2h(v1.z * no) | ((unsigned)f2h(v1.w * no) << 16);
    ((uint4*)xp)[i] = o;
}

__device__ __forceinline__ void acc_h8(float* a, uint4 u) {
    float2 f;
    f = h2f2(u.x); a[0] += f.x; a[1] += f.y;
    f = h2f2(u.y); a[2] += f.x; a[3] += f.y;
    f = h2f2(u.z); a[4] += f.x; a[5] += f.y;
    f = h2f2(u.w); a[6] += f.x; a[7] += f.y;
}

// ===========================================================================
// Fused gather + MFMA GEMM. One wave per 16-row tile:
//   phase 1: gather each row (8 edge-groups x 16B fp16 slices, 2x unroll),
//            xor-reduce, stage fp32 aggregate in wave-private LDS.
//   phase 2: A(16x64 fp16 from LDS) @ W(64x64 fp16 frags in regs) via
//            8 x mfma_f32_16x16x32_f16; epilogue: ni/bias/relu/norm_out.
// No __syncthreads: LDS region is wave-private.
// ===========================================================================
template <bool RELU, bool SCALE_OUT, bool OUT_HALF>
__global__ void __launch_bounds__(256)
gatherw_kernel(const unsigned int* __restrict__ xp,     // fp16 rows, 32 uints
               const int* __restrict__ rp,
               const unsigned int* __restrict__ edgeC,
               const int* __restrict__ cnt_in,
               const float* __restrict__ norm_out,
               const float* __restrict__ W,
               const float* __restrict__ bias,
               void* __restrict__ outv, int n_nodes) {
    __shared__ __align__(16) float agg[4][16][68];   // padded: bank-friendly
    int lane = threadIdx.x & 63;
    int wv   = threadIdx.x >> 6;
    int g    = lane >> 3, l8 = lane & 7;
    int quad = lane >> 4, l16 = lane & 15;
    int tile = (blockIdx.x * blockDim.x + threadIdx.x) >> 6;
    int row0 = tile * 16;
    if (row0 >= n_nodes) return;

    // --- W fragments (fp16) + bias, register-resident per wave ---
    half8 wf[2][4];
#pragma unroll
    for (int kt = 0; kt < 2; ++kt)
#pragma unroll
        for (int nt = 0; nt < 4; ++nt) {
            half8 h;
#pragma unroll
            for (int j = 0; j < 8; ++j) {
                int k = kt * 32 + quad * 8 + j;
                h[j] = (_Float16)W[k * D + nt * 16 + l16];
            }
            wf[kt][nt] = h;
        }
    float b4[4];
#pragma unroll
    for (int nt = 0; nt < 4; ++nt) b4[nt] = bias[nt * 16 + l16];

    // --- phase 1: gather 16 rows ---
    for (int rr = 0; rr < 16; ++rr) {
        int r = row0 + rr;
        float a[8];
#pragma unroll
        for (int j = 0; j < 8; ++j) a[j] = 0.0f;

        if (r < n_nodes) {
            int beg = rp[r];
            int deg = cnt_in[r];
            const unsigned int* el = edgeC + beg;
            int e = g;
            for (; e + 8 < deg; e += 16) {
                int s0 = (int)el[e], s1 = (int)el[e + 8];
                uint4 u = *(const uint4*)(xp + (size_t)s0 * 32 + l8 * 4);
                uint4 v = *(const uint4*)(xp + (size_t)s1 * 32 + l8 * 4);
                acc_h8(a, u);
                acc_h8(a, v);
            }
            for (; e < deg; e += 8) {
                int s0 = (int)el[e];
                uint4 u = *(const uint4*)(xp + (size_t)s0 * 32 + l8 * 4);
                acc_h8(a, u);
            }
        }
        // reduce across 8 edge-groups (lane bits 3..5)
#pragma unroll
        for (int off = 8; off < 64; off <<= 1) {
#pragma unroll
            for (int j = 0; j < 8; ++j) a[j] += __shfl_xor(a[j], off, 64);
        }
        if (g == 0) {   // lanes 0..7 write features [l8*8, l8*8+8)
            *(float4*)&agg[wv][rr][l8 * 8]     =
                make_float4(a[0], a[1], a[2], a[3]);
            *(float4*)&agg[wv][rr][l8 * 8 + 4] =
                make_float4(a[4], a[5], a[6], a[7]);
        }
    }

    // --- phase 2: A-frags from LDS (fp32 -> fp16), MFMA ---
    half8 af[2];
#pragma unroll
    for (int kt = 0; kt < 2; ++kt) {
        float4 f0 = *(const float4*)&agg[wv][l16][kt * 32 + quad * 8];
        float4 f1 = *(const float4*)&agg[wv][l16][kt * 32 + quad * 8 + 4];
        half8 h;
        h[0] = (_Float16)f0.x; h[1] = (_Float16)f0.y;
        h[2] = (_Float16)f0.z; h[3] = (_Float16)f0.w;
        h[4] = (_Float16)f1.x; h[5] = (_Float16)f1.y;
        h[6] = (_Float16)f1.z; h[7] = (_Float16)f1.w;
        af[kt] = h;
    }
    f32x4 c[4];
#pragma unroll
    for (int nt = 0; nt < 4; ++nt) {
        c[nt] = (f32x4){0.f, 0.f, 0.f, 0.f};
        c[nt] = __builtin_amdgcn_mfma_f32_16x16x32_f16(af[0], wf[0][nt],
                                                       c[nt], 0, 0, 0);
        c[nt] = __builtin_amdgcn_mfma_f32_16x16x32_f16(af[1], wf[1][nt],
                                                       c[nt], 0, 0, 0);
    }

    // --- epilogue: C layout col=lane&15, row=quad*4+reg ---
    float ni[4], no2[4];
    int rowv[4];
#pragma unroll
    for (int reg = 0; reg < 4; ++reg) {
        int row = row0 + quad * 4 + reg;
        rowv[reg] = row;
        if (row < n_nodes) {
            ni[reg] = rsqrtf(fmaxf((float)cnt_in[row], 1.0f));
            no2[reg] = SCALE_OUT ? norm_out[row] : 1.0f;
        } else {
            ni[reg] = 0.f; no2[reg] = 0.f;
        }
    }
#pragma unroll
    for (int nt = 0; nt < 4; ++nt) {
#pragma unroll
        for (int reg = 0; reg < 4; ++reg) {
            int row = rowv[reg];
            if (row < n_nodes) {
                float o = fmaf(c[nt][reg], ni[reg], b4[nt]);
                if (RELU) o = fmaxf(o, 0.0f);
                if (SCALE_OUT) o *= no2[reg];
                int col = nt * 16 + l16;
                if (OUT_HALF)
                    ((unsigned short*)outv)[(size_t)row * D + col] = f2h(o);
                else
                    ((float*)outv)[(size_t)row * D + col] = o;
            }
        }
    }
}

// ===========================================================================
// Minimal fallback (R1 atomic path) — only if workspace is tiny
// ===========================================================================
__global__ void degree_kernel(const int* __restrict__ src,
                              const int* __restrict__ dst,
                              float* __restrict__ deg_out,
                              float* __restrict__ deg_in, int n_edges) {
    int e = blockIdx.x * blockDim.x + threadIdx.x;
    if (e < n_edges) {
        atomicAdd(&deg_out[src[e]], 1.0f);
        atomicAdd(&deg_in[dst[e]], 1.0f);
    }
}
__global__ void norm_kernel(float* __restrict__ deg, int n) {
    int i = blockIdx.x * blockDim.x + threadIdx.x;
    if (i < n) deg[i] = rsqrtf(fmaxf(deg[i], 1.0f));
}
__global__ void spmm_kernel(const float* __restrict__ x,
                            const int* __restrict__ src,
                            const int* __restrict__ dst,
                            const float* __restrict__ norm_out,
                            float* __restrict__ agg, int n_edges) {
    int gid = blockIdx.x * blockDim.x + threadIdx.x;
    int e = gid >> 6, lane = threadIdx.x & 63;
    if (e < n_edges) {
        int s = src[e], d = dst[e];
        atomicAdd(&agg[(size_t)d * D + lane],
                  x[(size_t)s * D + lane] * norm_out[s]);
    }
}
template <bool RELU>
__global__ void gemm_kernel(const float* __restrict__ agg,
                            const float* __restrict__ norm_in,
                            const float* __restrict__ W,
                            const float* __restrict__ b,
                            float* __restrict__ out, int n_nodes) {
    __shared__ float Wl[D * D];
    for (int i = threadIdx.x; i < D * D; i += blockDim.x) Wl[i] = W[i];
    __syncthreads();
    int lane = threadIdx.x & 63, wave = threadIdx.x >> 6;
    int wpb = blockDim.x >> 6;
    float bj = b[lane];
    for (int row = blockIdx.x * wpb + wave; row < n_nodes;
         row += gridDim.x * wpb) {
        float aa = agg[(size_t)row * D + lane] * norm_in[row];
        float acc = bj;
#pragma unroll
        for (int k = 0; k < D; ++k)
            acc = fmaf(__shfl(aa, k, 64), Wl[k * D + lane], acc);
        if (RELU) acc = fmaxf(acc, 0.0f);
        out[(size_t)row * D + lane] = acc;
    }
}

// ===========================================================================
// Launch
// ===========================================================================
extern "C" void kernel_launch(void* const* d_in, const int* in_sizes, int n_in,
                              void* d_out, int out_size, void* d_ws, size_t ws_size,
                              hipStream_t stream) {
    const float* feats = (const float*)d_in[0];
    const int*   src   = (const int*)  d_in[1];
    const int*   dst   = (const int*)  d_in[2];
    const float* W1    = (const float*)d_in[3];
    const float* b1    = (const float*)d_in[4];
    const float* W2    = (const float*)d_in[5];
    const float* b2    = (const float*)d_in[6];
    float*       out   = (float*)d_out;

    const int n_nodes = in_sizes[0] / D;   // 100000
    const int n_edges = in_sizes[1];       // 1200000
    const size_t nd = (size_t)n_nodes * D;
    const int nb = (n_nodes + BSIZE - 1) >> BSHIFT;

    // Layout: [bufD nb*CAP u32 (reused as edgeC)][bufS nb*CAP u16]
    //         [xp1 half N*D][xa half N*D][rp N][cnt_in N][norm_out N]
    //         [curD 256][curS 256]
    size_t bufD_sz = (size_t)nb * CAP * 4;
    size_t bufS_sz = (size_t)nb * CAP * 2;
    size_t need = bufD_sz + bufS_sz + nd * 2 * 2 + (size_t)n_nodes * 12 + 2048;

    if (ws_size >= need && nb <= NBMAX) {
        char* base = (char*)d_ws;
        unsigned int*   bufD = (unsigned int*)base;
        unsigned short* bufS = (unsigned short*)(base + bufD_sz);
        unsigned int*   xp1  = (unsigned int*)(base + bufD_sz + bufS_sz);
        unsigned int*   xa   = (unsigned int*)((char*)xp1 + nd * 2);
        int*   rp       = (int*)((char*)xa + nd * 2);
        int*   cnt_in   = rp + n_nodes;
        float* norm_out = (float*)(cnt_in + n_nodes);
        int*   curD     = (int*)(norm_out + n_nodes);
        int*   curS     = curD + 256;

        hipMemsetAsync(curD, 0, 2048, stream);
        binA_kernel<<<256, 256, 0, stream>>>(src, dst, curD, curS, bufD, bufS,
                                             n_edges);
        binBC_kernel<<<2 * nb, 512, 0, stream>>>(bufD, bufD, bufS, curD, curS,
                                                 rp, cnt_in, norm_out,
                                                 n_nodes, nb);
        scale_kernel<<<(n_nodes * 8 + 255) / 256, 256, 0, stream>>>(
            feats, norm_out, xp1, n_nodes);

        int ntiles = (n_nodes + 15) / 16;
        int gblocks = (ntiles + 3) / 4;
        // Layer 1: xp1 -> xa (fp16, scaled by norm_out for next layer)
        gatherw_kernel<true, true, true><<<gblocks, 256, 0, stream>>>(
            xp1, rp, bufD, cnt_in, norm_out, W1, b1, xa, n_nodes);
        // Layer 2: xa -> final fp32 out
        gatherw_kernel<false, false, false><<<gblocks, 256, 0, stream>>>(
            xa, rp, bufD, cnt_in, norm_out, W2, b2, out, n_nodes);
        return;
    }

    // ---------------- fallback: R1 atomic path ----------------
    float* deg_out = (float*)d_ws;
    float* deg_in  = deg_out + n_nodes;
    float* agg     = deg_in + n_nodes;
    float* x       = out;

    hipMemsetAsync(d_ws, 0, (2 * (size_t)n_nodes + nd) * sizeof(float), stream);
    degree_kernel<<<(n_edges + 255) / 256, 256, 0, stream>>>(src, dst, deg_out,
                                                             deg_in, n_edges);
    norm_kernel<<<(2 * n_nodes + 255) / 256, 256, 0, stream>>>(deg_out,
                                                               2 * n_nodes);
    {
        long long threads = (long long)n_edges * 64;
        int blocks = (int)((threads + 255) / 256);
        spmm_kernel<<<blocks, 256, 0, stream>>>(feats, src, dst, deg_out, agg,
                                                n_edges);
    }
    gemm_kernel<true><<<(n_nodes + 3) / 4, 256, 0, stream>>>(agg, deg_in, W1,
                                                             b1, x, n_nodes);
    hipMemsetAsync(agg, 0, nd * sizeof(float), stream);
    {
        long long threads = (long long)n_edges * 64;
        int blocks = (int)((threads + 255) / 256);
        spmm_kernel<<<blocks, 256, 0, stream>>>(x, src, dst, deg_out, agg,
                                                n_edges);
    }
    gemm_kernel<false><<<(n_nodes + 3) / 4, 256, 0, stream>>>(agg, deg_in, W2,
                                                              b2, out, n_nodes);
}

// Round 7
// 215.271 us; speedup vs baseline: 1.4465x; 1.4465x over previous
//
#include <hip/hip_runtime.h>
#include <hip/hip_fp16.h>

#define D      64
#define BSHIFT 9
#define BSIZE  512    // nodes per bucket
#define NBMAX  256    // supports N <= 131072
#define CAP    8192   // edge capacity per bucket (lambda ~6.1k, 26 sigma)
#define CHUNK  4096   // binA LDS sort chunk

typedef _Float16 h2 __attribute__((ext_vector_type(2)));
union UH2 { unsigned u; h2 h; };

__device__ __forceinline__ unsigned short f2h(float f) {
    __half h = __float2half_rn(f);
    return *reinterpret_cast<unsigned short*>(&h);
}
__device__ __forceinline__ h2 u2h(unsigned u) { UH2 t; t.u = u; return t.h; }
__device__ __forceinline__ unsigned h2u(h2 h) { UH2 t; t.h = h; return t.u; }

// ===========================================================================
// binA v2: per-block LDS counting sort into NB coarse buckets, then
// COALESCED copy-out of dense per-bucket runs. ~200k global atomics total.
// ===========================================================================
__global__ void __launch_bounds__(256)
binA_kernel(const int* __restrict__ src, const int* __restrict__ dst,
            int* __restrict__ curD, int* __restrict__ curS,
            unsigned int* __restrict__ bufD,
            unsigned short* __restrict__ bufS, int n_edges) {
    __shared__ unsigned int   stD[CHUNK];
    __shared__ unsigned short stS[CHUNK];
    __shared__ unsigned char  stDB[CHUNK], stSB[CHUNK];
    __shared__ int histD[NBMAX], histS[NBMAX];
    __shared__ int offD[NBMAX], offS[NBMAX];
    __shared__ int bgD[NBMAX], bgS[NBMAX];

    int t = threadIdx.x;
    int per = (n_edges + gridDim.x - 1) / gridDim.x;
    int lo = blockIdx.x * per;
    int hi = min(lo + per, n_edges);

    for (int c0 = lo; c0 < hi; c0 += CHUNK) {
        int m = min(CHUNK, hi - c0);
        histD[t] = 0; histS[t] = 0;
        __syncthreads();
        for (int i = t; i < m; i += 256) {
            atomicAdd(&histD[dst[c0 + i] >> BSHIFT], 1);
            atomicAdd(&histS[src[c0 + i] >> BSHIFT], 1);
        }
        __syncthreads();
        int vD = histD[t], vS = histS[t];
        offD[t] = vD; offS[t] = vS;
        __syncthreads();
        for (int o = 1; o < 256; o <<= 1) {
            int xD = (t >= o) ? offD[t - o] : 0;
            int xS = (t >= o) ? offS[t - o] : 0;
            __syncthreads();
            offD[t] += xD; offS[t] += xS;
            __syncthreads();
        }
        offD[t] -= vD; offS[t] -= vS;            // exclusive scan
        bgD[t] = vD ? atomicAdd(&curD[t], vD) : 0;
        bgS[t] = vS ? atomicAdd(&curS[t], vS) : 0;
        __syncthreads();
        for (int i = t; i < m; i += 256) {       // LDS scatter (sorted)
            int s = src[c0 + i], d = dst[c0 + i];
            int bd = d >> BSHIFT;
            int p = atomicAdd(&offD[bd], 1);
            stD[p]  = (unsigned)s | ((unsigned)(d & (BSIZE - 1)) << 17);
            stDB[p] = (unsigned char)bd;
            int bs = s >> BSHIFT;
            int q = atomicAdd(&offS[bs], 1);
            stS[q]  = (unsigned short)(s & (BSIZE - 1));
            stSB[q] = (unsigned char)bs;
        }
        __syncthreads();
        for (int i = t; i < m; i += 256) {       // coalesced copy-out
            int bd = stDB[i];
            int lb = offD[bd] - histD[bd];       // excl base (off now = end)
            int gp = bgD[bd] + (i - lb);
            if (gp < CAP) bufD[(size_t)bd * CAP + gp] = stD[i];
            int bs = stSB[i];
            int lb2 = offS[bs] - histS[bs];
            int gq = bgS[bs] + (i - lb2);
            if (gq < CAP) bufS[(size_t)bs * CAP + gq] = stS[i];
        }
        __syncthreads();
    }
}

// ===========================================================================
// Phase B+C fused. blocks [0,nb): counting-sort dst-bucket in LDS, write
// dense edge list (aliases bufD), rp + cnt_in. blocks [nb,2nb): out-degree
// histogram -> norm_out.
// ===========================================================================
__global__ void __launch_bounds__(512)
binBC_kernel(const unsigned int* __restrict__ bufD,
             unsigned int* __restrict__ edgeC,        // == bufD (alias)
             const unsigned short* __restrict__ bufS,
             const int* __restrict__ curD, const int* __restrict__ curS,
             int* __restrict__ rp, int* __restrict__ cnt_in,
             float* __restrict__ norm_out, int n_nodes, int nb) {
    __shared__ int hist[BSIZE], off[BSIZE], cnt2[BSIZE];
    __shared__ int stage[CAP];
    int b = blockIdx.x, t = threadIdx.x;

    if (b < nb) {
        hist[t] = 0;
        __syncthreads();
        int m = min(curD[b], CAP);
        for (int e = t; e < m; e += 512)
            atomicAdd(&hist[bufD[(size_t)b * CAP + e] >> 17], 1);
        __syncthreads();
        int v = hist[t];
        off[t] = v;
        __syncthreads();
        for (int o = 1; o < 512; o <<= 1) {
            int x = (t >= o) ? off[t - o] : 0;
            __syncthreads();
            off[t] += x;
            __syncthreads();
        }
        int excl = off[t] - v;
        __syncthreads();
        off[t] = excl;
        cnt2[t] = 0;
        __syncthreads();
        for (int e = t; e < m; e += 512) {
            unsigned w = bufD[(size_t)b * CAP + e];
            int dl = w >> 17;
            int s  = (int)(w & 0x1FFFFu);
            int pos = off[dl] + atomicAdd(&cnt2[dl], 1);
            stage[pos] = s;
        }
        __syncthreads();
        for (int e = t; e < m; e += 512)
            edgeC[(size_t)b * CAP + e] = (unsigned)stage[e];
        int node = (b << BSHIFT) + t;
        if (node < n_nodes) {
            rp[node] = b * CAP + excl;
            cnt_in[node] = v;
        }
    } else {
        int b2 = b - nb;
        hist[t] = 0;
        __syncthreads();
        int m = min(curS[b2], CAP);
        for (int e = t; e < m; e += 512)
            atomicAdd(&hist[bufS[(size_t)b2 * CAP + e]], 1);
        __syncthreads();
        int node = (b2 << BSHIFT) + t;
        if (node < n_nodes)
            norm_out[node] = rsqrtf(fmaxf((float)hist[t], 1.0f));
    }
}

// ---- xp (fp16 packed) = x * norm_out; thread handles 8 features (16B) ----
__global__ void scale_kernel(const float* __restrict__ x,
                             const float* __restrict__ norm_out,
                             unsigned int* __restrict__ xp, int n_nodes) {
    int i = blockIdx.x * blockDim.x + threadIdx.x;
    if (i >= n_nodes * 8) return;
    int r = i >> 3;
    float no = norm_out[r];
    const float4* px = (const float4*)x + (size_t)i * 2;
    float4 v0 = px[0], v1 = px[1];
    uint4 o;
    o.x = (unsigned)f2h(v0.x * no) | ((unsigned)f2h(v0.y * no) << 16);
    o.y = (unsigned)f2h(v0.z * no) | ((unsigned)f2h(v0.w * no) << 16);
    o.z = (unsigned)f2h(v1.x * no) | ((unsigned)f2h(v1.y * no) << 16);
    o.w = (unsigned)f2h(v1.z * no) | ((unsigned)f2h(v1.w * no) << 16);
    ((uint4*)xp)[i] = o;
}

// ===========================================================================
// Fused gather + GEMV. One wave per row (grid-stride, ~8 rows/wave).
// 8 edge-groups of 8 lanes, each pulls a 16B fp16 slice, 2x unroll ->
// 16 rows in flight. Accumulate with v_pk_add_f16; xor-reduce packed;
// GEMV via 32 x (readlane + v_dot2_f32_f16) with W pairs in 32 VGPRs.
// ===========================================================================
template <bool RELU, bool SCALE_OUT, bool OUT_HALF>
__global__ void __launch_bounds__(256)
gatherw_kernel(const unsigned int* __restrict__ xp,     // fp16 rows, 32 uints
               const int* __restrict__ rp,
               const unsigned int* __restrict__ edgeC,
               const int* __restrict__ cnt_in,
               const float* __restrict__ norm_out,
               const float* __restrict__ W,
               const float* __restrict__ bias,
               void* __restrict__ outv, int n_nodes) {
    int lane = threadIdx.x & 63;
    int g    = lane >> 3, l8 = lane & 7;
    int wid  = (blockIdx.x * blockDim.x + threadIdx.x) >> 6;
    int nw   = (gridDim.x * blockDim.x) >> 6;

    // W pairs: wp[p] = (W[2p][lane], W[2p+1][lane]) as packed fp16
    h2 wp[32];
#pragma unroll
    for (int p = 0; p < 32; ++p) {
        h2 h;
        h.x = (_Float16)W[(2 * p) * D + lane];
        h.y = (_Float16)W[(2 * p + 1) * D + lane];
        wp[p] = h;
    }
    float bj = bias[lane];

    for (int r = wid; r < n_nodes; r += nw) {
        int beg = rp[r];
        int deg = cnt_in[r];
        const unsigned int* el = edgeC + beg;

        h2 a0 = (h2)0, a1 = (h2)0, a2 = (h2)0, a3 = (h2)0;
        int e = g;
        for (; e + 8 < deg; e += 16) {
            int s0 = (int)el[e], s1 = (int)el[e + 8];
            uint4 u = *(const uint4*)(xp + (size_t)s0 * 32 + l8 * 4);
            uint4 v = *(const uint4*)(xp + (size_t)s1 * 32 + l8 * 4);
            a0 += u2h(u.x); a1 += u2h(u.y); a2 += u2h(u.z); a3 += u2h(u.w);
            a0 += u2h(v.x); a1 += u2h(v.y); a2 += u2h(v.z); a3 += u2h(v.w);
        }
        for (; e < deg; e += 8) {
            int s0 = (int)el[e];
            uint4 u = *(const uint4*)(xp + (size_t)s0 * 32 + l8 * 4);
            a0 += u2h(u.x); a1 += u2h(u.y); a2 += u2h(u.z); a3 += u2h(u.w);
        }
        // reduce across 8 edge-groups (lane bits 3..5), packed adds
#pragma unroll
        for (int off = 8; off < 64; off <<= 1) {
            a0 += u2h(__shfl_xor(h2u(a0), off, 64));
            a1 += u2h(__shfl_xor(h2u(a1), off, 64));
            a2 += u2h(__shfl_xor(h2u(a2), off, 64));
            a3 += u2h(__shfl_xor(h2u(a3), off, 64));
        }
        // lane now holds feature pairs of slice l8: feats l8*8 + {0..7}
        unsigned au[4] = {h2u(a0), h2u(a1), h2u(a2), h2u(a3)};

        // GEMV: pair p = feats (2p,2p+1) lives in au[p&3] of lane p>>2
        float acc = 0.0f;
#pragma unroll
        for (int p = 0; p < 32; ++p) {
            UH2 t;
            t.u = __builtin_amdgcn_readlane(au[p & 3], p >> 2);
            acc = __builtin_amdgcn_fdot2(t.h, wp[p], acc, false);
        }

        float ni = rsqrtf(fmaxf((float)deg, 1.0f));
        float o  = fmaf(acc, ni, bj);
        if (RELU) o = fmaxf(o, 0.0f);
        if (SCALE_OUT) o *= norm_out[r];
        if (OUT_HALF)
            ((unsigned short*)outv)[(size_t)r * D + lane] = f2h(o);
        else
            ((float*)outv)[(size_t)r * D + lane] = o;
    }
}

// ===========================================================================
// Minimal fallback (R1 atomic path) — only if workspace is tiny
// ===========================================================================
__global__ void degree_kernel(const int* __restrict__ src,
                              const int* __restrict__ dst,
                              float* __restrict__ deg_out,
                              float* __restrict__ deg_in, int n_edges) {
    int e = blockIdx.x * blockDim.x + threadIdx.x;
    if (e < n_edges) {
        atomicAdd(&deg_out[src[e]], 1.0f);
        atomicAdd(&deg_in[dst[e]], 1.0f);
    }
}
__global__ void norm_kernel(float* __restrict__ deg, int n) {
    int i = blockIdx.x * blockDim.x + threadIdx.x;
    if (i < n) deg[i] = rsqrtf(fmaxf(deg[i], 1.0f));
}
__global__ void spmm_kernel(const float* __restrict__ x,
                            const int* __restrict__ src,
                            const int* __restrict__ dst,
                            const float* __restrict__ norm_out,
                            float* __restrict__ agg, int n_edges) {
    int gid = blockIdx.x * blockDim.x + threadIdx.x;
    int e = gid >> 6, lane = threadIdx.x & 63;
    if (e < n_edges) {
        int s = src[e], d = dst[e];
        atomicAdd(&agg[(size_t)d * D + lane],
                  x[(size_t)s * D + lane] * norm_out[s]);
    }
}
template <bool RELU>
__global__ void gemm_kernel(const float* __restrict__ agg,
                            const float* __restrict__ norm_in,
                            const float* __restrict__ W,
                            const float* __restrict__ b,
                            float* __restrict__ out, int n_nodes) {
    __shared__ float Wl[D * D];
    for (int i = threadIdx.x; i < D * D; i += blockDim.x) Wl[i] = W[i];
    __syncthreads();
    int lane = threadIdx.x & 63, wave = threadIdx.x >> 6;
    int wpb = blockDim.x >> 6;
    float bj = b[lane];
    for (int row = blockIdx.x * wpb + wave; row < n_nodes;
         row += gridDim.x * wpb) {
        float aa = agg[(size_t)row * D + lane] * norm_in[row];
        float acc = bj;
#pragma unroll
        for (int k = 0; k < D; ++k)
            acc = fmaf(__shfl(aa, k, 64), Wl[k * D + lane], acc);
        if (RELU) acc = fmaxf(acc, 0.0f);
        out[(size_t)row * D + lane] = acc;
    }
}

// ===========================================================================
// Launch
// ===========================================================================
extern "C" void kernel_launch(void* const* d_in, const int* in_sizes, int n_in,
                              void* d_out, int out_size, void* d_ws, size_t ws_size,
                              hipStream_t stream) {
    const float* feats = (const float*)d_in[0];
    const int*   src   = (const int*)  d_in[1];
    const int*   dst   = (const int*)  d_in[2];
    const float* W1    = (const float*)d_in[3];
    const float* b1    = (const float*)d_in[4];
    const float* W2    = (const float*)d_in[5];
    const float* b2    = (const float*)d_in[6];
    float*       out   = (float*)d_out;

    const int n_nodes = in_sizes[0] / D;   // 100000
    const int n_edges = in_sizes[1];       // 1200000
    const size_t nd = (size_t)n_nodes * D;
    const int nb = (n_nodes + BSIZE - 1) >> BSHIFT;

    // Layout: [bufD nb*CAP u32 (reused as edgeC)][bufS nb*CAP u16]
    //         [xp1 half N*D][xa half N*D][rp N][cnt_in N][norm_out N]
    //         [curD 256][curS 256]
    size_t bufD_sz = (size_t)nb * CAP * 4;
    size_t bufS_sz = (size_t)nb * CAP * 2;
    size_t need = bufD_sz + bufS_sz + nd * 2 * 2 + (size_t)n_nodes * 12 + 2048;

    if (ws_size >= need && nb <= NBMAX) {
        char* base = (char*)d_ws;
        unsigned int*   bufD = (unsigned int*)base;
        unsigned short* bufS = (unsigned short*)(base + bufD_sz);
        unsigned int*   xp1  = (unsigned int*)(base + bufD_sz + bufS_sz);
        unsigned int*   xa   = (unsigned int*)((char*)xp1 + nd * 2);
        int*   rp       = (int*)((char*)xa + nd * 2);
        int*   cnt_in   = rp + n_nodes;
        float* norm_out = (float*)(cnt_in + n_nodes);
        int*   curD     = (int*)(norm_out + n_nodes);
        int*   curS     = curD + 256;

        hipMemsetAsync(curD, 0, 2048, stream);
        binA_kernel<<<512, 256, 0, stream>>>(src, dst, curD, curS, bufD, bufS,
                                             n_edges);
        binBC_kernel<<<2 * nb, 512, 0, stream>>>(bufD, bufD, bufS, curD, curS,
                                                 rp, cnt_in, norm_out,
                                                 n_nodes, nb);
        scale_kernel<<<(n_nodes * 8 + 255) / 256, 256, 0, stream>>>(
            feats, norm_out, xp1, n_nodes);

        // Layer 1: xp1 -> xa (fp16, pre-scaled by norm_out for next layer)
        gatherw_kernel<true, true, true><<<3200, 256, 0, stream>>>(
            xp1, rp, bufD, cnt_in, norm_out, W1, b1, xa, n_nodes);
        // Layer 2: xa -> final fp32 out
        gatherw_kernel<false, false, false><<<3200, 256, 0, stream>>>(
            xa, rp, bufD, cnt_in, norm_out, W2, b2, out, n_nodes);
        return;
    }

    // ---------------- fallback: R1 atomic path ----------------
    float* deg_out = (float*)d_ws;
    float* deg_in  = deg_out + n_nodes;
    float* agg     = deg_in + n_nodes;
    float* x       = out;

    hipMemsetAsync(d_ws, 0, (2 * (size_t)n_nodes + nd) * sizeof(float), stream);
    degree_kernel<<<(n_edges + 255) / 256, 256, 0, stream>>>(src, dst, deg_out,
                                                             deg_in, n_edges);
    norm_kernel<<<(2 * n_nodes + 255) / 256, 256, 0, stream>>>(deg_out,
                                                               2 * n_nodes);
    {
        long long threads = (long long)n_edges * 64;
        int blocks = (int)((threads + 255) / 256);
        spmm_kernel<<<blocks, 256, 0, stream>>>(feats, src, dst, deg_out, agg,
                                                n_edges);
    }
    gemm_kernel<true><<<(n_nodes + 3) / 4, 256, 0, stream>>>(agg, deg_in, W1,
                                                             b1, x, n_nodes);
    hipMemsetAsync(agg, 0, nd * sizeof(float), stream);
    {
        long long threads = (long long)n_edges * 64;
        int blocks = (int)((threads + 255) / 256);
        spmm_kernel<<<blocks, 256, 0, stream>>>(x, src, dst, deg_out, agg,
                                                n_edges);
    }
    gemm_kernel<false><<<(n_nodes + 3) / 4, 256, 0, stream>>>(agg, deg_in, W2,
                                                              b2, out, n_nodes);
}

// Round 8
// 204.758 us; speedup vs baseline: 1.5207x; 1.0513x over previous
//
#include <hip/hip_runtime.h>
#include <hip/hip_fp16.h>

#define D      64
#define BSHIFT 9
#define BSIZE  512    // nodes per bucket
#define NBMAX  256    // supports N <= 131072
#define CAP    8192   // edge capacity per bucket (lambda ~6.1k, 26 sigma)
#define CHUNK  4096   // binA LDS sort chunk

typedef _Float16 h2 __attribute__((ext_vector_type(2)));
union UH2 { unsigned u; h2 h; };

__device__ __forceinline__ unsigned short f2h(float f) {
    __half h = __float2half_rn(f);
    return *reinterpret_cast<unsigned short*>(&h);
}
__device__ __forceinline__ h2 u2h(unsigned u) { UH2 t; t.u = u; return t.h; }
__device__ __forceinline__ unsigned h2u(h2 h) { UH2 t; t.h = h; return t.u; }

// ===========================================================================
// binA: per-block LDS counting sort into NB coarse buckets, then
// COALESCED copy-out of dense per-bucket runs. ~200k global atomics total.
// ===========================================================================
__global__ void __launch_bounds__(256)
binA_kernel(const int* __restrict__ src, const int* __restrict__ dst,
            int* __restrict__ curD, int* __restrict__ curS,
            unsigned int* __restrict__ bufD,
            unsigned short* __restrict__ bufS, int n_edges) {
    __shared__ unsigned int   stD[CHUNK];
    __shared__ unsigned short stS[CHUNK];
    __shared__ unsigned char  stDB[CHUNK], stSB[CHUNK];
    __shared__ int histD[NBMAX], histS[NBMAX];
    __shared__ int offD[NBMAX], offS[NBMAX];
    __shared__ int bgD[NBMAX], bgS[NBMAX];

    int t = threadIdx.x;
    int per = (n_edges + gridDim.x - 1) / gridDim.x;
    int lo = blockIdx.x * per;
    int hi = min(lo + per, n_edges);

    for (int c0 = lo; c0 < hi; c0 += CHUNK) {
        int m = min(CHUNK, hi - c0);
        histD[t] = 0; histS[t] = 0;
        __syncthreads();
        for (int i = t; i < m; i += 256) {
            atomicAdd(&histD[dst[c0 + i] >> BSHIFT], 1);
            atomicAdd(&histS[src[c0 + i] >> BSHIFT], 1);
        }
        __syncthreads();
        int vD = histD[t], vS = histS[t];
        offD[t] = vD; offS[t] = vS;
        __syncthreads();
        for (int o = 1; o < 256; o <<= 1) {
            int xD = (t >= o) ? offD[t - o] : 0;
            int xS = (t >= o) ? offS[t - o] : 0;
            __syncthreads();
            offD[t] += xD; offS[t] += xS;
            __syncthreads();
        }
        offD[t] -= vD; offS[t] -= vS;            // exclusive scan
        bgD[t] = vD ? atomicAdd(&curD[t], vD) : 0;
        bgS[t] = vS ? atomicAdd(&curS[t], vS) : 0;
        __syncthreads();
        for (int i = t; i < m; i += 256) {       // LDS scatter (sorted)
            int s = src[c0 + i], d = dst[c0 + i];
            int bd = d >> BSHIFT;
            int p = atomicAdd(&offD[bd], 1);
            stD[p]  = (unsigned)s | ((unsigned)(d & (BSIZE - 1)) << 17);
            stDB[p] = (unsigned char)bd;
            int bs = s >> BSHIFT;
            int q = atomicAdd(&offS[bs], 1);
            stS[q]  = (unsigned short)(s & (BSIZE - 1));
            stSB[q] = (unsigned char)bs;
        }
        __syncthreads();
        for (int i = t; i < m; i += 256) {       // coalesced copy-out
            int bd = stDB[i];
            int lb = offD[bd] - histD[bd];       // excl base (off now = end)
            int gp = bgD[bd] + (i - lb);
            if (gp < CAP) bufD[(size_t)bd * CAP + gp] = stD[i];
            int bs = stSB[i];
            int lb2 = offS[bs] - histS[bs];
            int gq = bgS[bs] + (i - lb2);
            if (gq < CAP) bufS[(size_t)bs * CAP + gq] = stS[i];
        }
        __syncthreads();
    }
}

// ===========================================================================
// binBC: blocks [0,nb): counting-sort dst-bucket in LDS -> dense edge list
// (aliases bufD) + rp + cnt_in. Blocks [nb,2nb): out-degree histogram ->
// norm_out AND fused fp16 staging xp1 = f16(feats * norm_out).
// ===========================================================================
__global__ void __launch_bounds__(512)
binBC_kernel(const unsigned int* __restrict__ bufD,
             unsigned int* __restrict__ edgeC,        // == bufD (alias)
             const unsigned short* __restrict__ bufS,
             const int* __restrict__ curD, const int* __restrict__ curS,
             int* __restrict__ rp, int* __restrict__ cnt_in,
             float* __restrict__ norm_out,
             const float* __restrict__ feats,
             uint2* __restrict__ xp1,
             int n_nodes, int nb) {
    __shared__ int hist[BSIZE], off[BSIZE], cnt2[BSIZE];
    __shared__ int stage[CAP];
    int b = blockIdx.x, t = threadIdx.x;

    if (b < nb) {
        hist[t] = 0;
        __syncthreads();
        int m = min(curD[b], CAP);
        for (int e = t; e < m; e += 512)
            atomicAdd(&hist[bufD[(size_t)b * CAP + e] >> 17], 1);
        __syncthreads();
        int v = hist[t];
        off[t] = v;
        __syncthreads();
        for (int o = 1; o < 512; o <<= 1) {
            int x = (t >= o) ? off[t - o] : 0;
            __syncthreads();
            off[t] += x;
            __syncthreads();
        }
        int excl = off[t] - v;
        __syncthreads();
        off[t] = excl;
        cnt2[t] = 0;
        __syncthreads();
        for (int e = t; e < m; e += 512) {
            unsigned w = bufD[(size_t)b * CAP + e];
            int dl = w >> 17;
            int s  = (int)(w & 0x1FFFFu);
            int pos = off[dl] + atomicAdd(&cnt2[dl], 1);
            stage[pos] = s;
        }
        __syncthreads();
        for (int e = t; e < m; e += 512)
            edgeC[(size_t)b * CAP + e] = (unsigned)stage[e];
        int node = (b << BSHIFT) + t;
        if (node < n_nodes) {
            rp[node] = b * CAP + excl;
            cnt_in[node] = v;
        }
    } else {
        int b2 = b - nb;
        int node0 = b2 << BSHIFT;
        hist[t] = 0;
        __syncthreads();
        int m = min(curS[b2], CAP);
        for (int e = t; e < m; e += 512)
            atomicAdd(&hist[bufS[(size_t)b2 * CAP + e]], 1);
        __syncthreads();
        int node = node0 + t;
        if (node < n_nodes)
            norm_out[node] = rsqrtf(fmaxf((float)hist[t], 1.0f));
        // fused scale: xp1[row] = fp16(feats[row] * norm_out[row])
        int m2 = min(BSIZE, n_nodes - node0);
        for (int i = t; i < m2 * 16; i += 512) {
            int row = i >> 4, c = i & 15;
            float no = rsqrtf(fmaxf((float)hist[row], 1.0f));
            float4 vv = ((const float4*)feats)[(size_t)(node0 + row) * 16 + c];
            uint2 o;
            o.x = (unsigned)f2h(vv.x * no) | ((unsigned)f2h(vv.y * no) << 16);
            o.y = (unsigned)f2h(vv.z * no) | ((unsigned)f2h(vv.w * no) << 16);
            xp1[(size_t)(node0 + row) * 16 + c] = o;
        }
    }
}

// ===========================================================================
// Fused gather + GEMV, TWO rows per wave:
//   groups 0-3 (lanes 0-31) gather row A, groups 4-7 (lanes 32-63) row B.
//   16 edges in flight per wave (same MLP as R7), xor-reduce only 2 levels
//   (covers both rows at once), dual dot2-GEMV per lane.
// ===========================================================================
template <bool RELU, bool SCALE_OUT, bool OUT_HALF>
__global__ void __launch_bounds__(256)
gatherw_kernel(const unsigned int* __restrict__ xp,     // fp16 rows, 32 uints
               const int* __restrict__ rp,
               const unsigned int* __restrict__ edgeC,
               const int* __restrict__ cnt_in,
               const float* __restrict__ norm_out,
               const float* __restrict__ W,
               const float* __restrict__ bias,
               void* __restrict__ outv, int n_nodes) {
    int lane = threadIdx.x & 63;
    int g    = lane >> 3, l8 = lane & 7;
    int half = g >> 2;             // 0 -> row A, 1 -> row B
    int g4   = g & 3;              // group within my row (0..3)
    int wid  = (blockIdx.x * blockDim.x + threadIdx.x) >> 6;
    int nw   = (gridDim.x * blockDim.x) >> 6;

    // W pairs: wp[p] = (W[2p][lane], W[2p+1][lane]) as packed fp16
    h2 wp[32];
#pragma unroll
    for (int p = 0; p < 32; ++p) {
        h2 h;
        h.x = (_Float16)W[(2 * p) * D + lane];
        h.y = (_Float16)W[(2 * p + 1) * D + lane];
        wp[p] = h;
    }
    float bj = bias[lane];

    int npairs = (n_nodes + 1) >> 1;
    for (int pr = wid; pr < npairs; pr += nw) {
        int r0 = pr * 2;
        int rme = r0 + half;                    // row this half-wave gathers
        int degme = 0, begme = 0;
        if (rme < n_nodes) { begme = rp[rme]; degme = cnt_in[rme]; }
        const unsigned int* el = edgeC + begme;

        h2 a0 = (h2)0, a1 = (h2)0, a2 = (h2)0, a3 = (h2)0;
        int e = g4;
        for (; e + 4 < degme; e += 8) {
            int s0 = (int)el[e], s1 = (int)el[e + 4];
            uint4 u = *(const uint4*)(xp + (size_t)s0 * 32 + l8 * 4);
            uint4 v = *(const uint4*)(xp + (size_t)s1 * 32 + l8 * 4);
            a0 += u2h(u.x); a1 += u2h(u.y); a2 += u2h(u.z); a3 += u2h(u.w);
            a0 += u2h(v.x); a1 += u2h(v.y); a2 += u2h(v.z); a3 += u2h(v.w);
        }
        for (; e < degme; e += 4) {
            int s0 = (int)el[e];
            uint4 u = *(const uint4*)(xp + (size_t)s0 * 32 + l8 * 4);
            a0 += u2h(u.x); a1 += u2h(u.y); a2 += u2h(u.z); a3 += u2h(u.w);
        }
        // reduce the 4 groups of each half (lane bits 3,4) — both rows at once
#pragma unroll
        for (int off = 8; off < 32; off <<= 1) {
            a0 += u2h(__shfl_xor(h2u(a0), off, 64));
            a1 += u2h(__shfl_xor(h2u(a1), off, 64));
            a2 += u2h(__shfl_xor(h2u(a2), off, 64));
            a3 += u2h(__shfl_xor(h2u(a3), off, 64));
        }
        // row A slice sums in lanes 0-7, row B in lanes 32-39
        unsigned au[4] = {h2u(a0), h2u(a1), h2u(a2), h2u(a3)};

        // dual GEMV: pair p of row A in lane p>>2, row B in lane 32+(p>>2)
        float accA = 0.0f, accB = 0.0f;
#pragma unroll
        for (int p = 0; p < 32; ++p) {
            UH2 ta, tb;
            ta.u = __builtin_amdgcn_readlane(au[p & 3], p >> 2);
            tb.u = __builtin_amdgcn_readlane(au[p & 3], 32 + (p >> 2));
            accA = __builtin_amdgcn_fdot2(ta.h, wp[p], accA, false);
            accB = __builtin_amdgcn_fdot2(tb.h, wp[p], accB, false);
        }

        int degA = __builtin_amdgcn_readlane(degme, 0);
        int degB = __builtin_amdgcn_readlane(degme, 32);
        {
            float ni = rsqrtf(fmaxf((float)degA, 1.0f));
            float o  = fmaf(accA, ni, bj);
            if (RELU) o = fmaxf(o, 0.0f);
            if (SCALE_OUT) o *= norm_out[r0];
            if (OUT_HALF)
                ((unsigned short*)outv)[(size_t)r0 * D + lane] = f2h(o);
            else
                ((float*)outv)[(size_t)r0 * D + lane] = o;
        }
        if (r0 + 1 < n_nodes) {
            float ni = rsqrtf(fmaxf((float)degB, 1.0f));
            float o  = fmaf(accB, ni, bj);
            if (RELU) o = fmaxf(o, 0.0f);
            if (SCALE_OUT) o *= norm_out[r0 + 1];
            if (OUT_HALF)
                ((unsigned short*)outv)[(size_t)(r0 + 1) * D + lane] = f2h(o);
            else
                ((float*)outv)[(size_t)(r0 + 1) * D + lane] = o;
        }
    }
}

// ===========================================================================
// Minimal fallback (R1 atomic path) — only if workspace is tiny
// ===========================================================================
__global__ void degree_kernel(const int* __restrict__ src,
                              const int* __restrict__ dst,
                              float* __restrict__ deg_out,
                              float* __restrict__ deg_in, int n_edges) {
    int e = blockIdx.x * blockDim.x + threadIdx.x;
    if (e < n_edges) {
        atomicAdd(&deg_out[src[e]], 1.0f);
        atomicAdd(&deg_in[dst[e]], 1.0f);
    }
}
__global__ void norm_kernel(float* __restrict__ deg, int n) {
    int i = blockIdx.x * blockDim.x + threadIdx.x;
    if (i < n) deg[i] = rsqrtf(fmaxf(deg[i], 1.0f));
}
__global__ void spmm_kernel(const float* __restrict__ x,
                            const int* __restrict__ src,
                            const int* __restrict__ dst,
                            const float* __restrict__ norm_out,
                            float* __restrict__ agg, int n_edges) {
    int gid = blockIdx.x * blockDim.x + threadIdx.x;
    int e = gid >> 6, lane = threadIdx.x & 63;
    if (e < n_edges) {
        int s = src[e], d = dst[e];
        atomicAdd(&agg[(size_t)d * D + lane],
                  x[(size_t)s * D + lane] * norm_out[s]);
    }
}
template <bool RELU>
__global__ void gemm_kernel(const float* __restrict__ agg,
                            const float* __restrict__ norm_in,
                            const float* __restrict__ W,
                            const float* __restrict__ b,
                            float* __restrict__ out, int n_nodes) {
    __shared__ float Wl[D * D];
    for (int i = threadIdx.x; i < D * D; i += blockDim.x) Wl[i] = W[i];
    __syncthreads();
    int lane = threadIdx.x & 63, wave = threadIdx.x >> 6;
    int wpb = blockDim.x >> 6;
    float bj = b[lane];
    for (int row = blockIdx.x * wpb + wave; row < n_nodes;
         row += gridDim.x * wpb) {
        float aa = agg[(size_t)row * D + lane] * norm_in[row];
        float acc = bj;
#pragma unroll
        for (int k = 0; k < D; ++k)
            acc = fmaf(__shfl(aa, k, 64), Wl[k * D + lane], acc);
        if (RELU) acc = fmaxf(acc, 0.0f);
        out[(size_t)row * D + lane] = acc;
    }
}

// ===========================================================================
// Launch
// ===========================================================================
extern "C" void kernel_launch(void* const* d_in, const int* in_sizes, int n_in,
                              void* d_out, int out_size, void* d_ws, size_t ws_size,
                              hipStream_t stream) {
    const float* feats = (const float*)d_in[0];
    const int*   src   = (const int*)  d_in[1];
    const int*   dst   = (const int*)  d_in[2];
    const float* W1    = (const float*)d_in[3];
    const float* b1    = (const float*)d_in[4];
    const float* W2    = (const float*)d_in[5];
    const float* b2    = (const float*)d_in[6];
    float*       out   = (float*)d_out;

    const int n_nodes = in_sizes[0] / D;   // 100000
    const int n_edges = in_sizes[1];       // 1200000
    const size_t nd = (size_t)n_nodes * D;
    const int nb = (n_nodes + BSIZE - 1) >> BSHIFT;

    // Layout: [bufD nb*CAP u32 (reused as edgeC)][bufS nb*CAP u16]
    //         [xp1 half N*D][xa half N*D][rp N][cnt_in N][norm_out N]
    //         [curD 256][curS 256]
    size_t bufD_sz = (size_t)nb * CAP * 4;
    size_t bufS_sz = (size_t)nb * CAP * 2;
    size_t need = bufD_sz + bufS_sz + nd * 2 * 2 + (size_t)n_nodes * 12 + 2048;

    if (ws_size >= need && nb <= NBMAX) {
        char* base = (char*)d_ws;
        unsigned int*   bufD = (unsigned int*)base;
        unsigned short* bufS = (unsigned short*)(base + bufD_sz);
        unsigned int*   xp1  = (unsigned int*)(base + bufD_sz + bufS_sz);
        unsigned int*   xa   = (unsigned int*)((char*)xp1 + nd * 2);
        int*   rp       = (int*)((char*)xa + nd * 2);
        int*   cnt_in   = rp + n_nodes;
        float* norm_out = (float*)(cnt_in + n_nodes);
        int*   curD     = (int*)(norm_out + n_nodes);
        int*   curS     = curD + 256;

        hipMemsetAsync(curD, 0, 2048, stream);
        binA_kernel<<<512, 256, 0, stream>>>(src, dst, curD, curS, bufD, bufS,
                                             n_edges);
        binBC_kernel<<<2 * nb, 512, 0, stream>>>(bufD, bufD, bufS, curD, curS,
                                                 rp, cnt_in, norm_out,
                                                 feats, (uint2*)xp1,
                                                 n_nodes, nb);

        // Layer 1: xp1 -> xa (fp16, pre-scaled by norm_out for next layer)
        gatherw_kernel<true, true, true><<<6400, 256, 0, stream>>>(
            xp1, rp, bufD, cnt_in, norm_out, W1, b1, xa, n_nodes);
        // Layer 2: xa -> final fp32 out
        gatherw_kernel<false, false, false><<<6400, 256, 0, stream>>>(
            xa, rp, bufD, cnt_in, norm_out, W2, b2, out, n_nodes);
        return;
    }

    // ---------------- fallback: R1 atomic path ----------------
    float* deg_out = (float*)d_ws;
    float* deg_in  = deg_out + n_nodes;
    float* agg     = deg_in + n_nodes;
    float* x       = out;

    hipMemsetAsync(d_ws, 0, (2 * (size_t)n_nodes + nd) * sizeof(float), stream);
    degree_kernel<<<(n_edges + 255) / 256, 256, 0, stream>>>(src, dst, deg_out,
                                                             deg_in, n_edges);
    norm_kernel<<<(2 * n_nodes + 255) / 256, 256, 0, stream>>>(deg_out,
                                                               2 * n_nodes);
    {
        long long threads = (long long)n_edges * 64;
        int blocks = (int)((threads + 255) / 256);
        spmm_kernel<<<blocks, 256, 0, stream>>>(feats, src, dst, deg_out, agg,
                                                n_edges);
    }
    gemm_kernel<true><<<(n_nodes + 3) / 4, 256, 0, stream>>>(agg, deg_in, W1,
                                                             b1, x, n_nodes);
    hipMemsetAsync(agg, 0, nd * sizeof(float), stream);
    {
        long long threads = (long long)n_edges * 64;
        int blocks = (int)((threads + 255) / 256);
        spmm_kernel<<<blocks, 256, 0, stream>>>(x, src, dst, deg_out, agg,
                                                n_edges);
    }
    gemm_kernel<false><<<(n_nodes + 3) / 4, 256, 0, stream>>>(agg, deg_in, W2,
                                                              b2, out, n_nodes);
}

// Round 10
// 197.227 us; speedup vs baseline: 1.5788x; 1.0382x over previous
//
#include <hip/hip_runtime.h>
#include <hip/hip_fp16.h>

#define D      64
#define BSHIFT 9
#define BSIZE  512    // nodes per bucket
#define NBMAX  256    // supports N <= 131072
#define CAP    8192   // edge capacity per bucket (lambda ~6.1k, 26 sigma)
#define CHUNK  4096   // binA LDS sort chunk

typedef _Float16 h2 __attribute__((ext_vector_type(2)));
union UH2 { unsigned u; h2 h; };

__device__ __forceinline__ unsigned short f2h(float f) {
    __half h = __float2half_rn(f);
    return *reinterpret_cast<unsigned short*>(&h);
}
__device__ __forceinline__ h2 u2h(unsigned u) { UH2 t; t.u = u; return t.h; }
__device__ __forceinline__ unsigned h2u(h2 h) { UH2 t; t.h = h; return t.u; }

// ===========================================================================
// binA: per-block LDS counting sort into NB coarse buckets, then
// COALESCED copy-out of dense per-bucket runs. ~200k global atomics total.
// ===========================================================================
__global__ void __launch_bounds__(256)
binA_kernel(const int* __restrict__ src, const int* __restrict__ dst,
            int* __restrict__ curD, int* __restrict__ curS,
            unsigned int* __restrict__ bufD,
            unsigned short* __restrict__ bufS, int n_edges) {
    __shared__ unsigned int   stD[CHUNK];
    __shared__ unsigned short stS[CHUNK];
    __shared__ unsigned char  stDB[CHUNK], stSB[CHUNK];
    __shared__ int histD[NBMAX], histS[NBMAX];
    __shared__ int offD[NBMAX], offS[NBMAX];
    __shared__ int bgD[NBMAX], bgS[NBMAX];

    int t = threadIdx.x;
    int per = (n_edges + gridDim.x - 1) / gridDim.x;
    int lo = blockIdx.x * per;
    int hi = min(lo + per, n_edges);

    for (int c0 = lo; c0 < hi; c0 += CHUNK) {
        int m = min(CHUNK, hi - c0);
        histD[t] = 0; histS[t] = 0;
        __syncthreads();
        for (int i = t; i < m; i += 256) {
            atomicAdd(&histD[dst[c0 + i] >> BSHIFT], 1);
            atomicAdd(&histS[src[c0 + i] >> BSHIFT], 1);
        }
        __syncthreads();
        int vD = histD[t], vS = histS[t];
        offD[t] = vD; offS[t] = vS;
        __syncthreads();
        for (int o = 1; o < 256; o <<= 1) {
            int xD = (t >= o) ? offD[t - o] : 0;
            int xS = (t >= o) ? offS[t - o] : 0;
            __syncthreads();
            offD[t] += xD; offS[t] += xS;
            __syncthreads();
        }
        offD[t] -= vD; offS[t] -= vS;            // exclusive scan
        bgD[t] = vD ? atomicAdd(&curD[t], vD) : 0;
        bgS[t] = vS ? atomicAdd(&curS[t], vS) : 0;
        __syncthreads();
        for (int i = t; i < m; i += 256) {       // LDS scatter (sorted)
            int s = src[c0 + i], d = dst[c0 + i];
            int bd = d >> BSHIFT;
            int p = atomicAdd(&offD[bd], 1);
            stD[p]  = (unsigned)s | ((unsigned)(d & (BSIZE - 1)) << 17);
            stDB[p] = (unsigned char)bd;
            int bs = s >> BSHIFT;
            int q = atomicAdd(&offS[bs], 1);
            stS[q]  = (unsigned short)(s & (BSIZE - 1));
            stSB[q] = (unsigned char)bs;
        }
        __syncthreads();
        for (int i = t; i < m; i += 256) {       // coalesced copy-out
            int bd = stDB[i];
            int lb = offD[bd] - histD[bd];       // excl base (off now = end)
            int gp = bgD[bd] + (i - lb);
            if (gp < CAP) bufD[(size_t)bd * CAP + gp] = stD[i];
            int bs = stSB[i];
            int lb2 = offS[bs] - histS[bs];
            int gq = bgS[bs] + (i - lb2);
            if (gq < CAP) bufS[(size_t)bs * CAP + gq] = stS[i];
        }
        __syncthreads();
    }
}

// ===========================================================================
// binBC: blocks [0,nb): counting-sort dst-bucket in LDS -> dense edge list
// (aliases bufD) + packed rpd = beg | (deg<<21). Blocks [nb,2nb): out-degree
// histogram -> norm_out AND fused fp16 staging xp1 = f16(feats * norm_out).
// ===========================================================================
__global__ void __launch_bounds__(512)
binBC_kernel(const unsigned int* __restrict__ bufD,
             unsigned int* __restrict__ edgeC,        // == bufD (alias)
             const unsigned short* __restrict__ bufS,
             const int* __restrict__ curD, const int* __restrict__ curS,
             unsigned int* __restrict__ rpd,
             float* __restrict__ norm_out,
             const float* __restrict__ feats,
             uint2* __restrict__ xp1,
             int n_nodes, int nb) {
    __shared__ int hist[BSIZE], off[BSIZE], cnt2[BSIZE];
    __shared__ int stage[CAP];
    int b = blockIdx.x, t = threadIdx.x;

    if (b < nb) {
        hist[t] = 0;
        __syncthreads();
        int m = min(curD[b], CAP);
        for (int e = t; e < m; e += 512)
            atomicAdd(&hist[bufD[(size_t)b * CAP + e] >> 17], 1);
        __syncthreads();
        int v = hist[t];
        off[t] = v;
        __syncthreads();
        for (int o = 1; o < 512; o <<= 1) {
            int x = (t >= o) ? off[t - o] : 0;
            __syncthreads();
            off[t] += x;
            __syncthreads();
        }
        int excl = off[t] - v;
        __syncthreads();
        off[t] = excl;
        cnt2[t] = 0;
        __syncthreads();
        for (int e = t; e < m; e += 512) {
            unsigned w = bufD[(size_t)b * CAP + e];
            int dl = w >> 17;
            int s  = (int)(w & 0x1FFFFu);
            int pos = off[dl] + atomicAdd(&cnt2[dl], 1);
            stage[pos] = s;
        }
        __syncthreads();
        for (int e = t; e < m; e += 512)
            edgeC[(size_t)b * CAP + e] = (unsigned)stage[e];
        int node = (b << BSHIFT) + t;
        if (node < n_nodes)
            rpd[node] = (unsigned)(b * CAP + excl) |
                        ((unsigned)min(v, 2047) << 21);
    } else {
        int b2 = b - nb;
        int node0 = b2 << BSHIFT;
        hist[t] = 0;
        __syncthreads();
        int m = min(curS[b2], CAP);
        for (int e = t; e < m; e += 512)
            atomicAdd(&hist[bufS[(size_t)b2 * CAP + e]], 1);
        __syncthreads();
        int node = node0 + t;
        if (node < n_nodes)
            norm_out[node] = rsqrtf(fmaxf((float)hist[t], 1.0f));
        // fused scale: xp1[row] = fp16(feats[row] * norm_out[row])
        int m2 = min(BSIZE, n_nodes - node0);
        for (int i = t; i < m2 * 16; i += 512) {
            int row = i >> 4, c = i & 15;
            float no = rsqrtf(fmaxf((float)hist[row], 1.0f));
            float4 vv = ((const float4*)feats)[(size_t)(node0 + row) * 16 + c];
            uint2 o;
            o.x = (unsigned)f2h(vv.x * no) | ((unsigned)f2h(vv.y * no) << 16);
            o.y = (unsigned)f2h(vv.z * no) | ((unsigned)f2h(vv.w * no) << 16);
            xp1[(size_t)(node0 + row) * 16 + c] = o;
        }
    }
}

// ===========================================================================
// Fused gather + GEMV, TWO rows per wave (lanes 0-31 row A, 32-63 row B).
// Packed rpd (1 load); edge list preloaded with ONE coalesced load and
// staged in wave-private LDS (written while converged). The divergent
// gather loops read edge ids via ds_read (no exec-mask data hazard,
// broadcast-conflict-free) -> chain rpd -> LDS -> xp, xp gathers independent.
// ===========================================================================
template <bool RELU, bool SCALE_OUT, bool OUT_HALF>
__global__ void __launch_bounds__(256)
gatherw_kernel(const unsigned int* __restrict__ xp,     // fp16 rows, 32 uints
               const unsigned int* __restrict__ rpd,
               const unsigned int* __restrict__ edgeC,
               const float* __restrict__ norm_out,
               const float* __restrict__ W,
               const float* __restrict__ bias,
               void* __restrict__ outv, int n_nodes) {
    __shared__ int eld[4][64];     // wave-private edge staging
    int lane   = threadIdx.x & 63;
    int wv     = threadIdx.x >> 6;
    int g      = lane >> 3, l8 = lane & 7;
    int half   = g >> 2;           // 0 -> row A, 1 -> row B
    int g4     = g & 3;            // group within my row (0..3)
    int base32 = lane & 32;
    int l32    = lane & 31;
    int wid  = (blockIdx.x * blockDim.x + threadIdx.x) >> 6;
    int nw   = (gridDim.x * blockDim.x) >> 6;

    // W pairs: wp[p] = (W[2p][lane], W[2p+1][lane]) as packed fp16
    h2 wp[32];
#pragma unroll
    for (int p = 0; p < 32; ++p) {
        h2 h;
        h.x = (_Float16)W[(2 * p) * D + lane];
        h.y = (_Float16)W[(2 * p + 1) * D + lane];
        wp[p] = h;
    }
    float bj = bias[lane];

    int npairs = (n_nodes + 1) >> 1;
    for (int pr = wid; pr < npairs; pr += nw) {
        int r0 = pr * 2;
        int rme = r0 + half;                    // row this half-wave gathers
        unsigned pk = (rme < n_nodes) ? rpd[rme] : 0u;
        int begme = (int)(pk & 0x1FFFFFu);
        int degme = (int)(pk >> 21);
        const unsigned int* el = edgeC + begme;

        int dmax = min(degme, 32);
        // one coalesced load per half; staged in LDS while fully converged
        eld[wv][lane] = (l32 < dmax) ? (int)el[l32] : 0;

        h2 a0 = (h2)0, a1 = (h2)0, a2 = (h2)0, a3 = (h2)0;
        int e = g4;
        for (; e + 4 < dmax; e += 8) {
            int s0 = eld[wv][base32 + e];
            int s1 = eld[wv][base32 + e + 4];
            uint4 u = *(const uint4*)(xp + (size_t)s0 * 32 + l8 * 4);
            uint4 v = *(const uint4*)(xp + (size_t)s1 * 32 + l8 * 4);
            a0 += u2h(u.x); a1 += u2h(u.y); a2 += u2h(u.z); a3 += u2h(u.w);
            a0 += u2h(v.x); a1 += u2h(v.y); a2 += u2h(v.z); a3 += u2h(v.w);
        }
        for (; e < dmax; e += 4) {
            int s0 = eld[wv][base32 + e];
            uint4 u = *(const uint4*)(xp + (size_t)s0 * 32 + l8 * 4);
            a0 += u2h(u.x); a1 += u2h(u.y); a2 += u2h(u.z); a3 += u2h(u.w);
        }
        for (int e2 = 32 + g4; e2 < degme; e2 += 4) {   // rare deg>32 tail
            int s0 = (int)el[e2];
            uint4 u = *(const uint4*)(xp + (size_t)s0 * 32 + l8 * 4);
            a0 += u2h(u.x); a1 += u2h(u.y); a2 += u2h(u.z); a3 += u2h(u.w);
        }
        // reduce the 4 groups of each half (lane bits 3,4) — both rows at once
#pragma unroll
        for (int off = 8; off < 32; off <<= 1) {
            a0 += u2h(__shfl_xor(h2u(a0), off, 64));
            a1 += u2h(__shfl_xor(h2u(a1), off, 64));
            a2 += u2h(__shfl_xor(h2u(a2), off, 64));
            a3 += u2h(__shfl_xor(h2u(a3), off, 64));
        }
        // row A slice sums in lanes 0-7, row B in lanes 32-39
        unsigned au[4] = {h2u(a0), h2u(a1), h2u(a2), h2u(a3)};

        // dual GEMV: pair p of row A in lane p>>2, row B in lane 32+(p>>2)
        float accA = 0.0f, accB = 0.0f;
#pragma unroll
        for (int p = 0; p < 32; ++p) {
            UH2 ta, tb;
            ta.u = __builtin_amdgcn_readlane(au[p & 3], p >> 2);
            tb.u = __builtin_amdgcn_readlane(au[p & 3], 32 + (p >> 2));
            accA = __builtin_amdgcn_fdot2(ta.h, wp[p], accA, false);
            accB = __builtin_amdgcn_fdot2(tb.h, wp[p], accB, false);
        }

        int degA = __builtin_amdgcn_readlane(degme, 0);
        int degB = __builtin_amdgcn_readlane(degme, 32);
        {
            float ni = rsqrtf(fmaxf((float)degA, 1.0f));
            float o  = fmaf(accA, ni, bj);
            if (RELU) o = fmaxf(o, 0.0f);
            if (SCALE_OUT) o *= norm_out[r0];
            if (OUT_HALF)
                ((unsigned short*)outv)[(size_t)r0 * D + lane] = f2h(o);
            else
                ((float*)outv)[(size_t)r0 * D + lane] = o;
        }
        if (r0 + 1 < n_nodes) {
            float ni = rsqrtf(fmaxf((float)degB, 1.0f));
            float o  = fmaf(accB, ni, bj);
            if (RELU) o = fmaxf(o, 0.0f);
            if (SCALE_OUT) o *= norm_out[r0 + 1];
            if (OUT_HALF)
                ((unsigned short*)outv)[(size_t)(r0 + 1) * D + lane] = f2h(o);
            else
                ((float*)outv)[(size_t)(r0 + 1) * D + lane] = o;
        }
    }
}

// ===========================================================================
// Minimal fallback (R1 atomic path) — only if workspace is tiny
// ===========================================================================
__global__ void degree_kernel(const int* __restrict__ src,
                              const int* __restrict__ dst,
                              float* __restrict__ deg_out,
                              float* __restrict__ deg_in, int n_edges) {
    int e = blockIdx.x * blockDim.x + threadIdx.x;
    if (e < n_edges) {
        atomicAdd(&deg_out[src[e]], 1.0f);
        atomicAdd(&deg_in[dst[e]], 1.0f);
    }
}
__global__ void norm_kernel(float* __restrict__ deg, int n) {
    int i = blockIdx.x * blockDim.x + threadIdx.x;
    if (i < n) deg[i] = rsqrtf(fmaxf(deg[i], 1.0f));
}
__global__ void spmm_kernel(const float* __restrict__ x,
                            const int* __restrict__ src,
                            const int* __restrict__ dst,
                            const float* __restrict__ norm_out,
                            float* __restrict__ agg, int n_edges) {
    int gid = blockIdx.x * blockDim.x + threadIdx.x;
    int e = gid >> 6, lane = threadIdx.x & 63;
    if (e < n_edges) {
        int s = src[e], d = dst[e];
        atomicAdd(&agg[(size_t)d * D + lane],
                  x[(size_t)s * D + lane] * norm_out[s]);
    }
}
template <bool RELU>
__global__ void gemm_kernel(const float* __restrict__ agg,
                            const float* __restrict__ norm_in,
                            const float* __restrict__ W,
                            const float* __restrict__ b,
                            float* __restrict__ out, int n_nodes) {
    __shared__ float Wl[D * D];
    for (int i = threadIdx.x; i < D * D; i += blockDim.x) Wl[i] = W[i];
    __syncthreads();
    int lane = threadIdx.x & 63, wave = threadIdx.x >> 6;
    int wpb = blockDim.x >> 6;
    float bj = b[lane];
    for (int row = blockIdx.x * wpb + wave; row < n_nodes;
         row += gridDim.x * wpb) {
        float aa = agg[(size_t)row * D + lane] * norm_in[row];
        float acc = bj;
#pragma unroll
        for (int k = 0; k < D; ++k)
            acc = fmaf(__shfl(aa, k, 64), Wl[k * D + lane], acc);
        if (RELU) acc = fmaxf(acc, 0.0f);
        out[(size_t)row * D + lane] = acc;
    }
}

// ===========================================================================
// Launch
// ===========================================================================
extern "C" void kernel_launch(void* const* d_in, const int* in_sizes, int n_in,
                              void* d_out, int out_size, void* d_ws, size_t ws_size,
                              hipStream_t stream) {
    const float* feats = (const float*)d_in[0];
    const int*   src   = (const int*)  d_in[1];
    const int*   dst   = (const int*)  d_in[2];
    const float* W1    = (const float*)d_in[3];
    const float* b1    = (const float*)d_in[4];
    const float* W2    = (const float*)d_in[5];
    const float* b2    = (const float*)d_in[6];
    float*       out   = (float*)d_out;

    const int n_nodes = in_sizes[0] / D;   // 100000
    const int n_edges = in_sizes[1];       // 1200000
    const size_t nd = (size_t)n_nodes * D;
    const int nb = (n_nodes + BSIZE - 1) >> BSHIFT;

    // Layout: [bufD nb*CAP u32 (reused as edgeC)][bufS nb*CAP u16]
    //         [xp1 half N*D][xa half N*D][rpd N][norm_out N][curD 256][curS 256]
    size_t bufD_sz = (size_t)nb * CAP * 4;
    size_t bufS_sz = (size_t)nb * CAP * 2;
    size_t need = bufD_sz + bufS_sz + nd * 2 * 2 + (size_t)n_nodes * 8 + 2048;

    if (ws_size >= need && nb <= NBMAX && (size_t)nb * CAP < (1u << 21)) {
        char* base = (char*)d_ws;
        unsigned int*   bufD = (unsigned int*)base;
        unsigned short* bufS = (unsigned short*)(base + bufD_sz);
        unsigned int*   xp1  = (unsigned int*)(base + bufD_sz + bufS_sz);
        unsigned int*   xa   = (unsigned int*)((char*)xp1 + nd * 2);
        unsigned int*   rpd  = (unsigned int*)((char*)xa + nd * 2);
        float* norm_out = (float*)(rpd + n_nodes);
        int*   curD     = (int*)(norm_out + n_nodes);
        int*   curS     = curD + 256;

        hipMemsetAsync(curD, 0, 2048, stream);
        binA_kernel<<<512, 256, 0, stream>>>(src, dst, curD, curS, bufD, bufS,
                                             n_edges);
        binBC_kernel<<<2 * nb, 512, 0, stream>>>(bufD, bufD, bufS, curD, curS,
                                                 rpd, norm_out,
                                                 feats, (uint2*)xp1,
                                                 n_nodes, nb);

        // Layer 1: xp1 -> xa (fp16, pre-scaled by norm_out for next layer)
        gatherw_kernel<true, true, true><<<6400, 256, 0, stream>>>(
            xp1, rpd, bufD, norm_out, W1, b1, xa, n_nodes);
        // Layer 2: xa -> final fp32 out
        gatherw_kernel<false, false, false><<<6400, 256, 0, stream>>>(
            xa, rpd, bufD, norm_out, W2, b2, out, n_nodes);
        return;
    }

    // ---------------- fallback: R1 atomic path ----------------
    float* deg_out = (float*)d_ws;
    float* deg_in  = deg_out + n_nodes;
    float* agg     = deg_in + n_nodes;
    float* x       = out;

    hipMemsetAsync(d_ws, 0, (2 * (size_t)n_nodes + nd) * sizeof(float), stream);
    degree_kernel<<<(n_edges + 255) / 256, 256, 0, stream>>>(src, dst, deg_out,
                                                             deg_in, n_edges);
    norm_kernel<<<(2 * n_nodes + 255) / 256, 256, 0, stream>>>(deg_out,
                                                               2 * n_nodes);
    {
        long long threads = (long long)n_edges * 64;
        int blocks = (int)((threads + 255) / 256);
        spmm_kernel<<<blocks, 256, 0, stream>>>(feats, src, dst, deg_out, agg,
                                                n_edges);
    }
    gemm_kernel<true><<<(n_nodes + 3) / 4, 256, 0, stream>>>(agg, deg_in, W1,
                                                             b1, x, n_nodes);
    hipMemsetAsync(agg, 0, nd * sizeof(float), stream);
    {
        long long threads = (long long)n_edges * 64;
        int blocks = (int)((threads + 255) / 256);
        spmm_kernel<<<blocks, 256, 0, stream>>>(x, src, dst, deg_out, agg,
                                                n_edges);
    }
    gemm_kernel<false><<<(n_nodes + 3) / 4, 256, 0, stream>>>(agg, deg_in, W2,
                                                              b2, out, n_nodes);
}